// Round 1
// baseline (12535.320 us; speedup 1.0000x reference)
//
#include <hip/hip_runtime.h>
#include <math.h>

#define N_NODES 200000
#define N_EDGES 3200000
#define NB      128
#define FIN     768
#define FH      64      // HID == OUT == 64
#define NC      4

// ---------------------------------------------------------------------------
// Degree (in-degree of dst) for both edge sets, accumulated as float.
__global__ __launch_bounds__(256) void k_deg(const int* __restrict__ dst_td,
                                             const int* __restrict__ dst_bu,
                                             float* __restrict__ deg_td,
                                             float* __restrict__ deg_bu) {
    int i = blockIdx.x * blockDim.x + threadIdx.x;
    if (i < N_EDGES) {
        atomicAdd(deg_td + dst_td[i], 1.0f);
        atomicAdd(deg_bu + dst_bu[i], 1.0f);
    }
}

// deg -> dinv = rsqrt(deg + 1)   (self-loop included; always > 0)
__global__ __launch_bounds__(256) void k_dinv(float* __restrict__ dv) {
    int i = blockIdx.x * blockDim.x + threadIdx.x;
    if (i < 2 * N_NODES) dv[i] = rsqrtf(dv[i] + 1.0f);
}

// ---------------------------------------------------------------------------
// GEMM1: XW_td = x @ W1_td, XW_bu = x @ W1_bu  (fused: 128 output cols)
// tile 64 rows x 128 cols, 256 threads, TK=16, each thread 8 rows x 4 cols
__global__ __launch_bounds__(256) void k_gemm1(const float* __restrict__ x,
                                               const float* __restrict__ Wtd,
                                               const float* __restrict__ Wbu,
                                               float* __restrict__ XWtd,
                                               float* __restrict__ XWbu) {
    __shared__ __align__(16) float As[16][64];    // [k][row]
    __shared__ __align__(16) float Ws[16][128];   // [k][col]
    const int tid  = threadIdx.x;
    const int row0 = blockIdx.x * 64;
    const int c0 = (tid & 31) * 4;   // 0..124
    const int r0 = (tid >> 5) * 8;   // 0..56
    float acc[8][4];
#pragma unroll
    for (int i = 0; i < 8; ++i)
#pragma unroll
        for (int j = 0; j < 4; ++j) acc[i][j] = 0.f;

    const int ar = tid >> 2;             // 0..63
    const int ak = (tid & 3) << 2;       // 0,4,8,12

    for (int k0 = 0; k0 < FIN; k0 += 16) {
        float4 av = *(const float4*)(x + (size_t)(row0 + ar) * FIN + k0 + ak);
        As[ak + 0][ar] = av.x;
        As[ak + 1][ar] = av.y;
        As[ak + 2][ar] = av.z;
        As[ak + 3][ar] = av.w;
#pragma unroll
        for (int t = 0; t < 2; ++t) {
            int f  = tid * 2 + t;            // 0..511
            int kk = f >> 5;                 // 0..15
            int c  = (f & 31) << 2;          // 0..124
            const float* Wp = (c < 64) ? (Wtd + (size_t)(k0 + kk) * 64 + c)
                                       : (Wbu + (size_t)(k0 + kk) * 64 + (c - 64));
            *(float4*)&Ws[kk][c] = *(const float4*)Wp;
        }
        __syncthreads();
#pragma unroll
        for (int kk = 0; kk < 16; ++kk) {
            float4 w = *(float4*)&Ws[kk][c0];
            float a[8];
            *(float4*)&a[0] = *(float4*)&As[kk][r0];
            *(float4*)&a[4] = *(float4*)&As[kk][r0 + 4];
#pragma unroll
            for (int i = 0; i < 8; ++i) {
                acc[i][0] = fmaf(a[i], w.x, acc[i][0]);
                acc[i][1] = fmaf(a[i], w.y, acc[i][1]);
                acc[i][2] = fmaf(a[i], w.z, acc[i][2]);
                acc[i][3] = fmaf(a[i], w.w, acc[i][3]);
            }
        }
        __syncthreads();
    }
    float* outb = (c0 < 64) ? (XWtd + (size_t)row0 * 64 + c0)
                            : (XWbu + (size_t)row0 * 64 + (c0 - 64));
#pragma unroll
    for (int i = 0; i < 8; ++i) {
        float4 v = make_float4(acc[i][0], acc[i][1], acc[i][2], acc[i][3]);
        *(float4*)(outb + (size_t)(r0 + i) * 64) = v;
    }
}

// ---------------------------------------------------------------------------
// RB[b][c] = sum_k relu(root[b,k]) * W2[(64+k), c]  for both branches
__global__ __launch_bounds__(128) void k_rb(const float* __restrict__ root,
                                            const float* __restrict__ W2td,
                                            const float* __restrict__ W2bu,
                                            float* __restrict__ RBtd,
                                            float* __restrict__ RBbu) {
    int b = blockIdx.x;
    int c = threadIdx.x;                 // 0..127
    const float* W2 = (c < 64) ? W2td : W2bu;
    int cc = c & 63;
    const float* rp = root + (size_t)b * FIN;
    float s = 0.f;
    for (int k = 0; k < FIN; ++k) {
        float r = fmaxf(rp[k], 0.f);
        s = fmaf(r, W2[(size_t)(64 + k) * 64 + cc], s);
    }
    (c < 64 ? RBtd : RBbu)[b * 64 + cc] = s;
}

// ---------------------------------------------------------------------------
// H init = bias + self-loop:  H[i,c] = b[c] + dinv[i]^2 * XW[i,c]
__global__ __launch_bounds__(256) void k_hinit(const float* __restrict__ XW,
                                               const float* __restrict__ dinv,
                                               const float* __restrict__ bias,
                                               float* __restrict__ H) {
    int i = blockIdx.x * blockDim.x + threadIdx.x;   // over N*16 float4 units
    if (i >= N_NODES * 16) return;
    int node = i >> 4;
    int q    = (i & 15) << 2;
    float dv  = dinv[node];
    float dv2 = dv * dv;
    float4 v  = *(const float4*)(XW + (size_t)node * 64 + q);
    float4 bb = *(const float4*)(bias + q);
    float4 o;
    o.x = fmaf(dv2, v.x, bb.x);
    o.y = fmaf(dv2, v.y, bb.y);
    o.z = fmaf(dv2, v.z, bb.z);
    o.w = fmaf(dv2, v.w, bb.w);
    *(float4*)(H + (size_t)node * 64 + q) = o;
}

// ---------------------------------------------------------------------------
// Edge scatter: out[d] += dinv[s]*dinv[d] * xw[s]   (4 edges per wave)
__global__ __launch_bounds__(256) void k_scatter(const int* __restrict__ src,
                                                 const int* __restrict__ dst,
                                                 const float* __restrict__ dinv,
                                                 const float* __restrict__ xw,
                                                 float* __restrict__ out) {
    int t  = blockIdx.x * blockDim.x + threadIdx.x;
    int e  = t >> 4;             // 16 lanes per edge
    int li = (t & 15) << 2;      // feature quad 0,4,...,60
    if (e >= N_EDGES) return;
    int s = src[e], d = dst[e];
    float nrm = dinv[s] * dinv[d];
    float4 v = *(const float4*)(xw + (size_t)s * 64 + li);
    float* op = out + (size_t)d * 64 + li;
    atomicAdd(op + 0, nrm * v.x);
    atomicAdd(op + 1, nrm * v.y);
    atomicAdd(op + 2, nrm * v.z);
    atomicAdd(op + 3, nrm * v.w);
}

// ---------------------------------------------------------------------------
// GEMM2 fused: XW2[i,:] = relu(H1[i,:]) @ W2[0:64,:] + RB[batch[i],:]
//              H2[i,:]  = b2 + dinv[i]^2 * XW2[i,:]
// tile 64 rows x 64 cols, 256 threads, thread = 4 rows x 4 cols
__global__ __launch_bounds__(256) void k_gemm2(const float* __restrict__ H1,
                                               const float* __restrict__ W2,
                                               const float* __restrict__ RB,
                                               const int* __restrict__ batch,
                                               const float* __restrict__ dinv,
                                               const float* __restrict__ b2,
                                               float* __restrict__ XW2,
                                               float* __restrict__ H2) {
    __shared__ __align__(16) float As[16][64];   // relu(H1) [k][row]
    __shared__ __align__(16) float Ws[16][64];   // W2a [k][col]
    const int tid  = threadIdx.x;
    const int row0 = blockIdx.x * 64;
    const int c0 = (tid & 15) * 4;   // 0..60
    const int r0 = (tid >> 4) * 4;   // 0..60
    float acc[4][4];
#pragma unroll
    for (int i = 0; i < 4; ++i)
#pragma unroll
        for (int j = 0; j < 4; ++j) acc[i][j] = 0.f;

    const int ar = tid >> 2;             // 0..63
    const int ak = (tid & 3) << 2;       // 0,4,8,12
    const int wk = tid >> 4;             // 0..15
    const int wc = (tid & 15) << 2;      // 0..60

    for (int k0 = 0; k0 < FH; k0 += 16) {
        float4 av = *(const float4*)(H1 + (size_t)(row0 + ar) * 64 + k0 + ak);
        As[ak + 0][ar] = fmaxf(av.x, 0.f);
        As[ak + 1][ar] = fmaxf(av.y, 0.f);
        As[ak + 2][ar] = fmaxf(av.z, 0.f);
        As[ak + 3][ar] = fmaxf(av.w, 0.f);
        *(float4*)&Ws[wk][wc] = *(const float4*)(W2 + (size_t)(k0 + wk) * 64 + wc);
        __syncthreads();
#pragma unroll
        for (int kk = 0; kk < 16; ++kk) {
            float4 w = *(float4*)&Ws[kk][c0];
            float4 a = *(float4*)&As[kk][r0];
            acc[0][0] = fmaf(a.x, w.x, acc[0][0]); acc[0][1] = fmaf(a.x, w.y, acc[0][1]);
            acc[0][2] = fmaf(a.x, w.z, acc[0][2]); acc[0][3] = fmaf(a.x, w.w, acc[0][3]);
            acc[1][0] = fmaf(a.y, w.x, acc[1][0]); acc[1][1] = fmaf(a.y, w.y, acc[1][1]);
            acc[1][2] = fmaf(a.y, w.z, acc[1][2]); acc[1][3] = fmaf(a.y, w.w, acc[1][3]);
            acc[2][0] = fmaf(a.z, w.x, acc[2][0]); acc[2][1] = fmaf(a.z, w.y, acc[2][1]);
            acc[2][2] = fmaf(a.z, w.z, acc[2][2]); acc[2][3] = fmaf(a.z, w.w, acc[2][3]);
            acc[3][0] = fmaf(a.w, w.x, acc[3][0]); acc[3][1] = fmaf(a.w, w.y, acc[3][1]);
            acc[3][2] = fmaf(a.w, w.z, acc[3][2]); acc[3][3] = fmaf(a.w, w.w, acc[3][3]);
        }
        __syncthreads();
    }
#pragma unroll
    for (int i = 0; i < 4; ++i) {
        int row = row0 + r0 + i;
        int bg  = batch[row];
        float4 rb  = *(const float4*)(RB + (size_t)bg * 64 + c0);
        float  dv  = dinv[row];
        float  dv2 = dv * dv;
        float4 bb  = *(const float4*)(b2 + c0);
        float4 xw2;
        xw2.x = acc[i][0] + rb.x; xw2.y = acc[i][1] + rb.y;
        xw2.z = acc[i][2] + rb.z; xw2.w = acc[i][3] + rb.w;
        float4 h2;
        h2.x = fmaf(dv2, xw2.x, bb.x); h2.y = fmaf(dv2, xw2.y, bb.y);
        h2.z = fmaf(dv2, xw2.z, bb.z); h2.w = fmaf(dv2, xw2.w, bb.w);
        *(float4*)(XW2 + (size_t)row * 64 + c0) = xw2;
        *(float4*)(H2  + (size_t)row * 64 + c0) = h2;
    }
}

// ---------------------------------------------------------------------------
__device__ __forceinline__ int lb_search(const int* __restrict__ a, int n, int v) {
    int lo = 0, hi = n;
    while (lo < hi) {
        int m = (lo + hi) >> 1;
        if (a[m] < v) lo = m + 1; else hi = m;
    }
    return lo;
}

// Pool per graph: pooled[b][0:64]  = mean over graph nodes of relu(H2)
//                 pooled[b][64:128]= cnt>0 ? H1[rootindex[b]] : 0
__global__ __launch_bounds__(512) void k_pool(const float* __restrict__ H2,
                                              const float* __restrict__ H1,
                                              const int* __restrict__ batch,
                                              const int* __restrict__ rootindex,
                                              float* __restrict__ pooled) {
    int b    = blockIdx.x;
    int lane = threadIdx.x & 63;
    int wv   = threadIdx.x >> 6;      // 0..7
    int start = lb_search(batch, N_NODES, b);
    int end   = lb_search(batch, N_NODES, b + 1);
    float acc = 0.f;
    for (int i = start + wv; i < end; i += 8)
        acc += fmaxf(H2[(size_t)i * 64 + lane], 0.f);
    __shared__ float red[8][64];
    red[wv][lane] = acc;
    __syncthreads();
    if (wv == 0) {
        float s = 0.f;
#pragma unroll
        for (int w = 0; w < 8; ++w) s += red[w][lane];
        int cnt = end - start;
        float inv = 1.0f / fmaxf((float)cnt, 1.0f);
        pooled[b * 128 + lane] = s * inv;
        float rootv = (cnt > 0) ? H1[(size_t)rootindex[b] * 64 + lane] : 0.f;
        pooled[b * 128 + 64 + lane] = rootv;
    }
}

// ---------------------------------------------------------------------------
// Final FC + log_softmax.  feat = [pooled_bu | pooled_td]  (bu FIRST)
__global__ __launch_bounds__(128) void k_final(const float* __restrict__ ptd,
                                               const float* __restrict__ pbu,
                                               const float* __restrict__ fcW,
                                               const float* __restrict__ fcb,
                                               float* __restrict__ out) {
    int b = threadIdx.x;
    if (b >= NB) return;
    float l[4] = {fcb[0], fcb[1], fcb[2], fcb[3]};
    for (int j = 0; j < 256; ++j) {
        float f = (j < 128) ? pbu[b * 128 + j] : ptd[b * 128 + (j - 128)];
#pragma unroll
        for (int c = 0; c < 4; ++c) l[c] = fmaf(f, fcW[j * 4 + c], l[c]);
    }
    float m = fmaxf(fmaxf(l[0], l[1]), fmaxf(l[2], l[3]));
    float s = expf(l[0] - m) + expf(l[1] - m) + expf(l[2] - m) + expf(l[3] - m);
    float ls = logf(s);
#pragma unroll
    for (int c = 0; c < 4; ++c) out[b * 4 + c] = l[c] - m - ls;
}

// ---------------------------------------------------------------------------
extern "C" void kernel_launch(void* const* d_in, const int* in_sizes, int n_in,
                              void* d_out, int out_size, void* d_ws, size_t ws_size,
                              hipStream_t stream) {
    const float* x     = (const float*)d_in[0];
    const int*   ei    = (const int*)d_in[1];    // [2,E]: src, dst
    const int*   bei   = (const int*)d_in[2];
    const int*   batch = (const int*)d_in[3];
    const int*   rooti = (const int*)d_in[4];
    const float* root  = (const float*)d_in[5];
    const float* W1td  = (const float*)d_in[6];
    const float* b1td  = (const float*)d_in[7];
    const float* W2td  = (const float*)d_in[8];
    const float* b2td  = (const float*)d_in[9];
    const float* W1bu  = (const float*)d_in[10];
    const float* b1bu  = (const float*)d_in[11];
    const float* W2bu  = (const float*)d_in[12];
    const float* b2bu  = (const float*)d_in[13];
    const float* fcW   = (const float*)d_in[14];
    const float* fcb   = (const float*)d_in[15];
    float* out = (float*)d_out;

    float* ws = (float*)d_ws;
    size_t o = 0;
    const size_t NF = (size_t)N_NODES * 64;
    float* XWtd   = ws + o; o += NF;
    float* XWbu   = ws + o; o += NF;
    float* H1     = ws + o; o += NF;
    float* H2     = ws + o; o += NF;
    float* dinvtd = ws + o; o += N_NODES;
    float* dinvbu = ws + o; o += N_NODES;
    float* RBtd   = ws + o; o += (size_t)NB * 64;
    float* RBbu   = ws + o; o += (size_t)NB * 64;
    float* pooltd = ws + o; o += (size_t)NB * 128;
    float* poolbu = ws + o; o += (size_t)NB * 128;

    // degrees (zero first; dinv buffers are contiguous)
    hipMemsetAsync(dinvtd, 0, 2 * (size_t)N_NODES * sizeof(float), stream);
    k_deg<<<(N_EDGES + 255) / 256, 256, 0, stream>>>(ei + N_EDGES, bei + N_EDGES,
                                                     dinvtd, dinvbu);
    k_dinv<<<(2 * N_NODES + 255) / 256, 256, 0, stream>>>(dinvtd);

    // big fused matmul + root-projection
    k_gemm1<<<N_NODES / 64, 256, 0, stream>>>(x, W1td, W1bu, XWtd, XWbu);
    k_rb<<<NB, 128, 0, stream>>>(root, W2td, W2bu, RBtd, RBbu);

    const int scat_blocks = (N_EDGES * 16) / 256;   // 200000
    const int hin_blocks  = (N_NODES * 16 + 255) / 256;

    // ---- td branch ----
    k_hinit<<<hin_blocks, 256, 0, stream>>>(XWtd, dinvtd, b1td, H1);
    k_scatter<<<scat_blocks, 256, 0, stream>>>(ei, ei + N_EDGES, dinvtd, XWtd, H1);
    k_gemm2<<<N_NODES / 64, 256, 0, stream>>>(H1, W2td, RBtd, batch, dinvtd, b2td,
                                              XWtd /*XW2*/, H2);
    k_scatter<<<scat_blocks, 256, 0, stream>>>(ei, ei + N_EDGES, dinvtd, XWtd, H2);
    k_pool<<<NB, 512, 0, stream>>>(H2, H1, batch, rooti, pooltd);

    // ---- bu branch ----
    k_hinit<<<hin_blocks, 256, 0, stream>>>(XWbu, dinvbu, b1bu, H1);
    k_scatter<<<scat_blocks, 256, 0, stream>>>(bei, bei + N_EDGES, dinvbu, XWbu, H1);
    k_gemm2<<<N_NODES / 64, 256, 0, stream>>>(H1, W2bu, RBbu, batch, dinvbu, b2bu,
                                              XWbu /*XW2*/, H2);
    k_scatter<<<scat_blocks, 256, 0, stream>>>(bei, bei + N_EDGES, dinvbu, XWbu, H2);
    k_pool<<<NB, 512, 0, stream>>>(H2, H1, batch, rooti, poolbu);

    // ---- head ----
    k_final<<<1, 128, 0, stream>>>(pooltd, poolbu, fcW, fcb, out);
}

// Round 2
// 2749.315 us; speedup vs baseline: 4.5594x; 4.5594x over previous
//
#include <hip/hip_runtime.h>
#include <math.h>

#define N_NODES 200000
#define N_EDGES 3200000
#define NB      128
#define FIN     768
#define FH      64      // HID == OUT == 64
#define NC      4

#define SCAN_TILE 1024                      // 256 threads x 4 elems
#define NBLK ((N_NODES + SCAN_TILE - 1) / SCAN_TILE)   // 196 (<=256 required)

// ---------------------------------------------------------------------------
// Integer in-degree of dst for both edge sets. degi[0..N)=td, [N..2N)=bu.
__global__ __launch_bounds__(256) void k_degi(const int* __restrict__ dst_td,
                                              const int* __restrict__ dst_bu,
                                              int* __restrict__ degi) {
    int i = blockIdx.x * blockDim.x + threadIdx.x;
    if (i < N_EDGES) {
        atomicAdd(degi + dst_td[i], 1);
        atomicAdd(degi + N_NODES + dst_bu[i], 1);
    }
}

// dinv = rsqrt(deg + 1)   (self-loop included; always > 0)
__global__ __launch_bounds__(256) void k_dinv(const int* __restrict__ degi,
                                              float* __restrict__ dv) {
    int i = blockIdx.x * blockDim.x + threadIdx.x;
    if (i < 2 * N_NODES) dv[i] = rsqrtf((float)degi[i] + 1.0f);
}

// ---------------------------------------------------------------------------
// Prefix-scan of degrees -> rowptr (exclusive), cursor (copy of rowptr).
__global__ __launch_bounds__(256) void k_scanA(const int* __restrict__ deg,
                                               int* __restrict__ bsum) {
    __shared__ int sh[256];
    int t = threadIdx.x, b = blockIdx.x;
    int base = b * SCAN_TILE + t * 4;
    int s = 0;
#pragma unroll
    for (int j = 0; j < 4; ++j) {
        int idx = base + j;
        if (idx < N_NODES) s += deg[idx];
    }
    sh[t] = s;
    __syncthreads();
    for (int off = 128; off > 0; off >>= 1) {
        if (t < off) sh[t] += sh[t + off];
        __syncthreads();
    }
    if (t == 0) bsum[b] = sh[0];
}

__global__ __launch_bounds__(256) void k_scanB(const int* __restrict__ bsum,
                                               int* __restrict__ boff) {
    __shared__ int sh[256];
    int t = threadIdx.x;
    int v = (t < NBLK) ? bsum[t] : 0;
    sh[t] = v;
    __syncthreads();
    for (int off = 1; off < 256; off <<= 1) {
        int a = (t >= off) ? sh[t - off] : 0;
        __syncthreads();
        sh[t] += a;
        __syncthreads();
    }
    if (t < NBLK) boff[t] = sh[t] - v;   // exclusive
}

__global__ __launch_bounds__(256) void k_scanC(const int* __restrict__ deg,
                                               const int* __restrict__ boff,
                                               int* __restrict__ rowptr,
                                               int* __restrict__ cursor) {
    __shared__ int sh[256];
    int t = threadIdx.x, b = blockIdx.x;
    int base = b * SCAN_TILE + t * 4;
    int v[4];
    int tot = 0;
#pragma unroll
    for (int j = 0; j < 4; ++j) {
        int idx = base + j;
        v[j] = (idx < N_NODES) ? deg[idx] : 0;
        tot += v[j];
    }
    sh[t] = tot;
    __syncthreads();
    for (int off = 1; off < 256; off <<= 1) {
        int a = (t >= off) ? sh[t - off] : 0;
        __syncthreads();
        sh[t] += a;
        __syncthreads();
    }
    int run = boff[b] + sh[t] - tot;     // global exclusive prefix at base
#pragma unroll
    for (int j = 0; j < 4; ++j) {
        int idx = base + j;
        if (idx < N_NODES) {
            rowptr[idx] = run;
            cursor[idx] = run;
            run += v[j];
        }
    }
    if (b == 0 && t == 0) rowptr[N_NODES] = N_EDGES;
}

// Counting-sort edges into CSR by dst (order within a row is arbitrary).
__global__ __launch_bounds__(256) void k_fill(const int* __restrict__ src,
                                              const int* __restrict__ dst,
                                              int* __restrict__ cursor,
                                              int* __restrict__ csr) {
    int e = blockIdx.x * blockDim.x + threadIdx.x;
    if (e < N_EDGES) {
        int d = dst[e];
        int pos = atomicAdd(cursor + d, 1);
        csr[pos] = src[e];
    }
}

// ---------------------------------------------------------------------------
// GEMM1: XW_td = x @ W1_td, XW_bu = x @ W1_bu  (fused: 128 output cols)
__global__ __launch_bounds__(256) void k_gemm1(const float* __restrict__ x,
                                               const float* __restrict__ Wtd,
                                               const float* __restrict__ Wbu,
                                               float* __restrict__ XWtd,
                                               float* __restrict__ XWbu) {
    __shared__ __align__(16) float As[16][64];    // [k][row]
    __shared__ __align__(16) float Ws[16][128];   // [k][col]
    const int tid  = threadIdx.x;
    const int row0 = blockIdx.x * 64;
    const int c0 = (tid & 31) * 4;   // 0..124
    const int r0 = (tid >> 5) * 8;   // 0..56
    float acc[8][4];
#pragma unroll
    for (int i = 0; i < 8; ++i)
#pragma unroll
        for (int j = 0; j < 4; ++j) acc[i][j] = 0.f;

    const int ar = tid >> 2;             // 0..63
    const int ak = (tid & 3) << 2;       // 0,4,8,12

    for (int k0 = 0; k0 < FIN; k0 += 16) {
        float4 av = *(const float4*)(x + (size_t)(row0 + ar) * FIN + k0 + ak);
        As[ak + 0][ar] = av.x;
        As[ak + 1][ar] = av.y;
        As[ak + 2][ar] = av.z;
        As[ak + 3][ar] = av.w;
#pragma unroll
        for (int t = 0; t < 2; ++t) {
            int f  = tid * 2 + t;            // 0..511
            int kk = f >> 5;                 // 0..15
            int c  = (f & 31) << 2;          // 0..124
            const float* Wp = (c < 64) ? (Wtd + (size_t)(k0 + kk) * 64 + c)
                                       : (Wbu + (size_t)(k0 + kk) * 64 + (c - 64));
            *(float4*)&Ws[kk][c] = *(const float4*)Wp;
        }
        __syncthreads();
#pragma unroll
        for (int kk = 0; kk < 16; ++kk) {
            float4 w = *(float4*)&Ws[kk][c0];
            float a[8];
            *(float4*)&a[0] = *(float4*)&As[kk][r0];
            *(float4*)&a[4] = *(float4*)&As[kk][r0 + 4];
#pragma unroll
            for (int i = 0; i < 8; ++i) {
                acc[i][0] = fmaf(a[i], w.x, acc[i][0]);
                acc[i][1] = fmaf(a[i], w.y, acc[i][1]);
                acc[i][2] = fmaf(a[i], w.z, acc[i][2]);
                acc[i][3] = fmaf(a[i], w.w, acc[i][3]);
            }
        }
        __syncthreads();
    }
    float* outb = (c0 < 64) ? (XWtd + (size_t)row0 * 64 + c0)
                            : (XWbu + (size_t)row0 * 64 + (c0 - 64));
#pragma unroll
    for (int i = 0; i < 8; ++i) {
        float4 v = make_float4(acc[i][0], acc[i][1], acc[i][2], acc[i][3]);
        *(float4*)(outb + (size_t)(r0 + i) * 64) = v;
    }
}

// ---------------------------------------------------------------------------
// RB[b][c] = sum_k relu(root[b,k]) * W2[(64+k), c]  for both branches
__global__ __launch_bounds__(128) void k_rb(const float* __restrict__ root,
                                            const float* __restrict__ W2td,
                                            const float* __restrict__ W2bu,
                                            float* __restrict__ RBtd,
                                            float* __restrict__ RBbu) {
    int b = blockIdx.x;
    int c = threadIdx.x;                 // 0..127
    const float* W2 = (c < 64) ? W2td : W2bu;
    int cc = c & 63;
    const float* rp = root + (size_t)b * FIN;
    float s = 0.f;
    for (int k = 0; k < FIN; ++k) {
        float r = fmaxf(rp[k], 0.f);
        s = fmaf(r, W2[(size_t)(64 + k) * 64 + cc], s);
    }
    (c < 64 ? RBtd : RBbu)[b * 64 + cc] = s;
}

// ---------------------------------------------------------------------------
// CSR gather: out[i] = bias + dinv[i]^2 * xw[i] + sum_e dinv[i]*dinv[s]*xw[s]
// quarter-wave (16 lanes x float4) per node
__global__ __launch_bounds__(256) void k_gather(const int* __restrict__ rowptr,
                                                const int* __restrict__ csr,
                                                const float* __restrict__ dinv,
                                                const float* __restrict__ xw,
                                                const float* __restrict__ bias,
                                                float* __restrict__ out) {
    int t    = blockIdx.x * blockDim.x + threadIdx.x;
    int node = t >> 4;
    int li   = (t & 15) << 2;
    if (node >= N_NODES) return;
    float dv = dinv[node];
    float4 bb = *(const float4*)(bias + li);
    float4 sv = *(const float4*)(xw + (size_t)node * 64 + li);
    float dv2 = dv * dv;
    float4 acc;
    acc.x = fmaf(dv2, sv.x, bb.x);
    acc.y = fmaf(dv2, sv.y, bb.y);
    acc.z = fmaf(dv2, sv.z, bb.z);
    acc.w = fmaf(dv2, sv.w, bb.w);
    int e0 = rowptr[node], e1 = rowptr[node + 1];
    for (int e = e0; e < e1; ++e) {
        int s = csr[e];
        float nrm = dv * dinv[s];
        float4 v = *(const float4*)(xw + (size_t)s * 64 + li);
        acc.x = fmaf(nrm, v.x, acc.x);
        acc.y = fmaf(nrm, v.y, acc.y);
        acc.z = fmaf(nrm, v.z, acc.z);
        acc.w = fmaf(nrm, v.w, acc.w);
    }
    *(float4*)(out + (size_t)node * 64 + li) = acc;
}

// ---------------------------------------------------------------------------
// GEMM2 fused: XW2[i,:] = relu(H1[i,:]) @ W2[0:64,:] + RB[batch[i],:]
__global__ __launch_bounds__(256) void k_gemm2(const float* __restrict__ H1,
                                               const float* __restrict__ W2,
                                               const float* __restrict__ RB,
                                               const int* __restrict__ batch,
                                               float* __restrict__ XW2) {
    __shared__ __align__(16) float As[16][64];   // relu(H1) [k][row]
    __shared__ __align__(16) float Ws[16][64];   // W2a [k][col]
    const int tid  = threadIdx.x;
    const int row0 = blockIdx.x * 64;
    const int c0 = (tid & 15) * 4;   // 0..60
    const int r0 = (tid >> 4) * 4;   // 0..60
    float acc[4][4];
#pragma unroll
    for (int i = 0; i < 4; ++i)
#pragma unroll
        for (int j = 0; j < 4; ++j) acc[i][j] = 0.f;

    const int ar = tid >> 2;             // 0..63
    const int ak = (tid & 3) << 2;       // 0,4,8,12
    const int wk = tid >> 4;             // 0..15
    const int wc = (tid & 15) << 2;      // 0..60

    for (int k0 = 0; k0 < FH; k0 += 16) {
        float4 av = *(const float4*)(H1 + (size_t)(row0 + ar) * 64 + k0 + ak);
        As[ak + 0][ar] = fmaxf(av.x, 0.f);
        As[ak + 1][ar] = fmaxf(av.y, 0.f);
        As[ak + 2][ar] = fmaxf(av.z, 0.f);
        As[ak + 3][ar] = fmaxf(av.w, 0.f);
        *(float4*)&Ws[wk][wc] = *(const float4*)(W2 + (size_t)(k0 + wk) * 64 + wc);
        __syncthreads();
#pragma unroll
        for (int kk = 0; kk < 16; ++kk) {
            float4 w = *(float4*)&Ws[kk][c0];
            float4 a = *(float4*)&As[kk][r0];
            acc[0][0] = fmaf(a.x, w.x, acc[0][0]); acc[0][1] = fmaf(a.x, w.y, acc[0][1]);
            acc[0][2] = fmaf(a.x, w.z, acc[0][2]); acc[0][3] = fmaf(a.x, w.w, acc[0][3]);
            acc[1][0] = fmaf(a.y, w.x, acc[1][0]); acc[1][1] = fmaf(a.y, w.y, acc[1][1]);
            acc[1][2] = fmaf(a.y, w.z, acc[1][2]); acc[1][3] = fmaf(a.y, w.w, acc[1][3]);
            acc[2][0] = fmaf(a.z, w.x, acc[2][0]); acc[2][1] = fmaf(a.z, w.y, acc[2][1]);
            acc[2][2] = fmaf(a.z, w.z, acc[2][2]); acc[2][3] = fmaf(a.z, w.w, acc[2][3]);
            acc[3][0] = fmaf(a.w, w.x, acc[3][0]); acc[3][1] = fmaf(a.w, w.y, acc[3][1]);
            acc[3][2] = fmaf(a.w, w.z, acc[3][2]); acc[3][3] = fmaf(a.w, w.w, acc[3][3]);
        }
        __syncthreads();
    }
#pragma unroll
    for (int i = 0; i < 4; ++i) {
        int row = row0 + r0 + i;
        int bg  = batch[row];
        float4 rb = *(const float4*)(RB + (size_t)bg * 64 + c0);
        float4 xw2;
        xw2.x = acc[i][0] + rb.x; xw2.y = acc[i][1] + rb.y;
        xw2.z = acc[i][2] + rb.z; xw2.w = acc[i][3] + rb.w;
        *(float4*)(XW2 + (size_t)row * 64 + c0) = xw2;
    }
}

// ---------------------------------------------------------------------------
__device__ __forceinline__ int lb_search(const int* __restrict__ a, int n, int v) {
    int lo = 0, hi = n;
    while (lo < hi) {
        int m = (lo + hi) >> 1;
        if (a[m] < v) lo = m + 1; else hi = m;
    }
    return lo;
}

// Pool per graph: pooled[b][0:64]  = mean over graph nodes of relu(H2)
//                 pooled[b][64:128]= cnt>0 ? H1[rootindex[b]] : 0
__global__ __launch_bounds__(512) void k_pool(const float* __restrict__ H2,
                                              const float* __restrict__ H1,
                                              const int* __restrict__ batch,
                                              const int* __restrict__ rootindex,
                                              float* __restrict__ pooled) {
    int b    = blockIdx.x;
    int lane = threadIdx.x & 63;
    int wv   = threadIdx.x >> 6;      // 0..7
    int start = lb_search(batch, N_NODES, b);
    int end   = lb_search(batch, N_NODES, b + 1);
    float acc = 0.f;
    for (int i = start + wv; i < end; i += 8)
        acc += fmaxf(H2[(size_t)i * 64 + lane], 0.f);
    __shared__ float red[8][64];
    red[wv][lane] = acc;
    __syncthreads();
    if (wv == 0) {
        float s = 0.f;
#pragma unroll
        for (int w = 0; w < 8; ++w) s += red[w][lane];
        int cnt = end - start;
        float inv = 1.0f / fmaxf((float)cnt, 1.0f);
        pooled[b * 128 + lane] = s * inv;
        float rootv = (cnt > 0) ? H1[(size_t)rootindex[b] * 64 + lane] : 0.f;
        pooled[b * 128 + 64 + lane] = rootv;
    }
}

// ---------------------------------------------------------------------------
// Final FC + log_softmax.  feat = [pooled_bu | pooled_td]  (bu FIRST)
__global__ __launch_bounds__(128) void k_final(const float* __restrict__ ptd,
                                               const float* __restrict__ pbu,
                                               const float* __restrict__ fcW,
                                               const float* __restrict__ fcb,
                                               float* __restrict__ out) {
    int b = threadIdx.x;
    if (b >= NB) return;
    float l[4] = {fcb[0], fcb[1], fcb[2], fcb[3]};
    for (int j = 0; j < 256; ++j) {
        float f = (j < 128) ? pbu[b * 128 + j] : ptd[b * 128 + (j - 128)];
#pragma unroll
        for (int c = 0; c < 4; ++c) l[c] = fmaf(f, fcW[j * 4 + c], l[c]);
    }
    float m = fmaxf(fmaxf(l[0], l[1]), fmaxf(l[2], l[3]));
    float s = expf(l[0] - m) + expf(l[1] - m) + expf(l[2] - m) + expf(l[3] - m);
    float ls = logf(s);
#pragma unroll
    for (int c = 0; c < 4; ++c) out[b * 4 + c] = l[c] - m - ls;
}

// ---------------------------------------------------------------------------
extern "C" void kernel_launch(void* const* d_in, const int* in_sizes, int n_in,
                              void* d_out, int out_size, void* d_ws, size_t ws_size,
                              hipStream_t stream) {
    const float* x     = (const float*)d_in[0];
    const int*   ei    = (const int*)d_in[1];    // [2,E]: src, dst
    const int*   bei   = (const int*)d_in[2];
    const int*   batch = (const int*)d_in[3];
    const int*   rooti = (const int*)d_in[4];
    const float* root  = (const float*)d_in[5];
    const float* W1td  = (const float*)d_in[6];
    const float* b1td  = (const float*)d_in[7];
    const float* W2td  = (const float*)d_in[8];
    const float* b2td  = (const float*)d_in[9];
    const float* W1bu  = (const float*)d_in[10];
    const float* b1bu  = (const float*)d_in[11];
    const float* W2bu  = (const float*)d_in[12];
    const float* b2bu  = (const float*)d_in[13];
    const float* fcW   = (const float*)d_in[14];
    const float* fcb   = (const float*)d_in[15];
    float* out = (float*)d_out;

    char* ws = (char*)d_ws;
    size_t o = 0;
    const size_t NF = (size_t)N_NODES * 64;
    auto alloc_f = [&](size_t n) { float* p = (float*)(ws + o); o += n * 4; return p; };
    auto alloc_i = [&](size_t n) { int*   p = (int*)  (ws + o); o += n * 4; return p; };

    float* XWtd   = alloc_f(NF);
    float* XWbu   = alloc_f(NF);
    float* H1     = alloc_f(NF);
    float* H2     = alloc_f(NF);
    float* dinvtd = alloc_f(N_NODES);
    float* dinvbu = alloc_f(N_NODES);
    float* RBtd   = alloc_f((size_t)NB * 64);
    float* RBbu   = alloc_f((size_t)NB * 64);
    float* pooltd = alloc_f((size_t)NB * 128);
    float* poolbu = alloc_f((size_t)NB * 128);
    int* degi     = alloc_i(2 * (size_t)N_NODES);    // td | bu
    int* rp_td    = alloc_i(N_NODES + 1);
    int* rp_bu    = alloc_i(N_NODES + 1);
    int* cur_td   = alloc_i(N_NODES);
    int* cur_bu   = alloc_i(N_NODES);
    int* bsum     = alloc_i(256);
    int* boff     = alloc_i(256);
    int* csr_td   = alloc_i(N_EDGES);
    int* csr_bu   = alloc_i(N_EDGES);

    const int eb = (N_EDGES + 255) / 256;            // 12500

    // degrees + dinv
    hipMemsetAsync(degi, 0, 2 * (size_t)N_NODES * sizeof(int), stream);
    k_degi<<<eb, 256, 0, stream>>>(ei + N_EDGES, bei + N_EDGES, degi);
    k_dinv<<<(2 * N_NODES + 255) / 256, 256, 0, stream>>>(degi, dinvtd);

    // CSR build (td then bu; scan scratch reused — stream-ordered)
    k_scanA<<<NBLK, 256, 0, stream>>>(degi, bsum);
    k_scanB<<<1, 256, 0, stream>>>(bsum, boff);
    k_scanC<<<NBLK, 256, 0, stream>>>(degi, boff, rp_td, cur_td);
    k_fill<<<eb, 256, 0, stream>>>(ei, ei + N_EDGES, cur_td, csr_td);

    k_scanA<<<NBLK, 256, 0, stream>>>(degi + N_NODES, bsum);
    k_scanB<<<1, 256, 0, stream>>>(bsum, boff);
    k_scanC<<<NBLK, 256, 0, stream>>>(degi + N_NODES, boff, rp_bu, cur_bu);
    k_fill<<<eb, 256, 0, stream>>>(bei, bei + N_EDGES, cur_bu, csr_bu);

    // big fused matmul + root-projection
    k_gemm1<<<N_NODES / 64, 256, 0, stream>>>(x, W1td, W1bu, XWtd, XWbu);
    k_rb<<<NB, 128, 0, stream>>>(root, W2td, W2bu, RBtd, RBbu);

    const int gb = (N_NODES * 16) / 256;             // 12500

    // ---- td branch ----
    k_gather<<<gb, 256, 0, stream>>>(rp_td, csr_td, dinvtd, XWtd, b1td, H1);
    k_gemm2<<<N_NODES / 64, 256, 0, stream>>>(H1, W2td, RBtd, batch, XWtd /*XW2*/);
    k_gather<<<gb, 256, 0, stream>>>(rp_td, csr_td, dinvtd, XWtd, b2td, H2);
    k_pool<<<NB, 512, 0, stream>>>(H2, H1, batch, rooti, pooltd);

    // ---- bu branch ----
    k_gather<<<gb, 256, 0, stream>>>(rp_bu, csr_bu, dinvbu, XWbu, b1bu, H1);
    k_gemm2<<<N_NODES / 64, 256, 0, stream>>>(H1, W2bu, RBbu, batch, XWbu /*XW2*/);
    k_gather<<<gb, 256, 0, stream>>>(rp_bu, csr_bu, dinvbu, XWbu, b2bu, H2);
    k_pool<<<NB, 512, 0, stream>>>(H2, H1, batch, rooti, poolbu);

    // ---- head ----
    k_final<<<1, 128, 0, stream>>>(pooltd, poolbu, fcW, fcb, out);
}